// Round 10
// baseline (156.877 us; speedup 1.0000x reference)
//
#include <hip/hip_runtime.h>
#include <hip/hip_bf16.h>

// SupConLoss, B=8192, D=128, T=0.1. Output: single fp32 scalar.
//
// Pipeline (tiny memset + 4 launches):
//   0) hipMemsetAsync  — zeroes 100 class counters + final accumulators
//      (412 B).
//   1) supcon_convert  — dtype detection; features -> bf16 ws copy (RTNE),
//      labels -> int32; builds per-class row LISTS with ONE int atomicAdd
//      per row (8192 messages — r7/r9 lesson: 1M fp32 atomics cost ~30us of
//      device-coherence message throughput; replication didn't help, so
//      eliminate the messages, don't spread them).
//   2) supcon_classsum — g[c][d] = sum of listed rows' bf16-rounded values.
//      100 blocks x 128 threads, pure coalesced loads, direct store, NO
//      atomics. Enables p_i = a_i . g[lab_i] (exact modulo fp32 reorder).
//   3) supcon_main     — fused bf16-MFMA GEMM (F.F^T) + exp accumulation.
//      Register-prefetched B from L2 (issue-early/use-late, 1 iter ahead),
//      no LDS staging, no barriers, no inline asm (r9 structure, clean:
//      no spill, WRITE 288KB). NC=16 -> 1024 blocks = 4 blocks/CU: r9's
//      counters showed Occupancy 17% with VGPR=104 (4 waves/SIMD possible)
//      — the grid was starving the CUs, latency exposed.
//   4) supcon_reduce   — e partials + p_i = a_i.g[lab_i] dot -> loss.
//      n_i from exact label histogram. Diagonal removed exactly (same exp2
//      on same input). Last-block-atomic finalization (ticket zeroed by
//      memset -> graph-replay safe).
//
// Math: with ANY fixed shift M, per row i:
//   mean_log_prob_i = 10*p_i/n_i - M - log(sum_{j!=i} exp(s_ij - M))
// (shift cancels; M=10.5 >= max s_ij for unit-norm). exp folded to exp2.
//
// History:
//  r1: launch_bounds(256,4) -> VGPR=64 spill, 46->215us. Never clamp.
//  r2: NC=16 + n_acc removal: main ~46 -> ~36us. 41us harness fill floor.
//  r3: no-LDS direct-L2, NO prefetch: 68.7us. Serial load->use chain.
//  r4: 2-phase LDS staging: main ~35us. Not staging-latency-bound.
//  r5/r6: classsum kernels both slow (LDS-atomic chain 88us; uniform-scan
//      ~38us). p-dot 64/128-dim bug (+0.0625) fixed r6.
//  r7: classsum as 1M fp32 atomics in convert: convert ~30us.
//  r8: sched_barrier(0) graft -> regalloc spill (WRITE 74MB, 51us).
//  r9: reg-prefetch main CLEAN: 41.8us, Occ 17%, VGPR 104, no spill.
//      All utils ~15% -> grid-starved latency-bound. This round: NC=16
//      (4 blocks/CU) + gather-list classsum (zero fp32 atomics).

#define BB 8192
#define DD 128
#define NCLS 100
#define NC 16                // column chunks (grid.x): 1024 blocks = 4/CU
#define COLCHUNK (BB / NC)   // 512 cols per WG
#define TILEC 64             // cols per iteration
#define ITERS (COLCHUNK / TILEC)   // 8 (even: 2x-unrolled loop)
#define TEMP_INV 10.0f
#define MSHIFT 10.5f
#define C1F 14.426950408889634f    /* 10*log2(e)    */
#define C2F -15.148297929334116f   /* -10.5*log2(e) */

typedef __bf16 bf16x8 __attribute__((ext_vector_type(8)));
typedef float floatx4 __attribute__((ext_vector_type(4)));

__device__ inline float fast_exp2(float x) {
#if __has_builtin(__builtin_amdgcn_exp2f)
    return __builtin_amdgcn_exp2f(x);
#else
    return exp2f(x);
#endif
}

__device__ inline unsigned short f2bf(float f) {           // RTNE fp32->bf16
    unsigned u = __float_as_uint(f);
    return (unsigned short)((u + 0x7FFFu + ((u >> 16) & 1u)) >> 16);
}

__device__ inline float bf2f(unsigned short s) {
    return __uint_as_float(((unsigned)s) << 16);
}

// ---- 1) canonicalize (+ detect + per-class row lists) ----
__global__ __launch_bounds__(256) void supcon_convert(
    const void* __restrict__ fin, const void* __restrict__ lin,
    unsigned short* __restrict__ fbf, int* __restrict__ lab,
    int* __restrict__ cls_cnt, int* __restrict__ cls_list)
{
    // Per-wave dtype detection: every wave reads the same 128-short feature
    // header and 128-int label header, butterfly-reduces across its own 64
    // lanes -> every thread holds the verdict, no LDS/sync needed.
    int lane = threadIdx.x & 63;
    unsigned ue = ((unsigned)((const unsigned short*)fin)[2 * lane]) << 16;
    float fe = __uint_as_float(ue);
    float ve = fe * fe;
    int odd_or = ((const int*)lin)[2 * lane + 1];
#pragma unroll
    for (int m = 1; m < 64; m <<= 1) {
        ve += __shfl_xor(ve, m, 64);
        odd_or |= __shfl_xor(odd_or, m, 64);
    }
    // true bf16 unit rows: sum sq of 64 even slots of row 0 is ~0.5.
    bool f_bf16 = (ve > 0.05f) && (ve < 4.0f);   // NaN-safe: NaN -> false
    bool l_i64  = (odd_or == 0);

    int gid = blockIdx.x * 256 + threadIdx.x;    // 262144 threads x 4 elements
    if (!f_bf16) {
        float4 v = ((const float4*)fin)[gid];
        ushort4 o;
        o.x = f2bf(v.x); o.y = f2bf(v.y); o.z = f2bf(v.z); o.w = f2bf(v.w);
        ((ushort4*)fbf)[gid] = o;
    } else {
        ((ushort4*)fbf)[gid] = ((const ushort4*)fin)[gid];
    }

    const int* L = (const int*)lin;
    // One list-builder thread per row (32 threads cover one 128-dim row).
    if ((gid & 31) == 0) {
        int row = gid >> 5;
        int c = l_i64 ? L[2 * row] : L[row];
        int slot = atomicAdd(&cls_cnt[c], 1);
        cls_list[(size_t)c * BB + slot] = row;
    }
    if (blockIdx.x < 32) {
        int li = blockIdx.x * 256 + threadIdx.x;
        lab[li] = l_i64 ? L[2 * li] : L[li];
    }
}

// ---- 2) gather class sums: g[c][d] = sum over listed rows (no atomics) ----
__global__ __launch_bounds__(128) void supcon_classsum(
    const unsigned short* __restrict__ Fb, const int* __restrict__ cls_cnt,
    const int* __restrict__ cls_list, float* __restrict__ g)
{
    const int c = blockIdx.x;                    // class 0..99
    const int d = threadIdx.x;                   // dim 0..127
    const int n = cls_cnt[c];
    const int* lst = cls_list + (size_t)c * BB;
    float a0 = 0.f, a1 = 0.f, a2 = 0.f, a3 = 0.f;
    int i = 0;
    for (; i + 4 <= n; i += 4) {                 // 4 independent loads in flight
        int r0 = lst[i], r1 = lst[i + 1], r2 = lst[i + 2], r3 = lst[i + 3];
        a0 += bf2f(Fb[(size_t)r0 * DD + d]);
        a1 += bf2f(Fb[(size_t)r1 * DD + d]);
        a2 += bf2f(Fb[(size_t)r2 * DD + d]);
        a3 += bf2f(Fb[(size_t)r3 * DD + d]);
    }
    for (; i < n; ++i) a0 += bf2f(Fb[(size_t)lst[i] * DD + d]);
    g[c * DD + d] = (a0 + a1) + (a2 + a3);
}

// Load the B fragments for 64-col tile `itx` into register set bb[2][4].
// Fully unrolled -> all indices compile-time (rule #20: registers, never
// scratch). Per instr: 64 lanes read 16 cols x 64B contiguous segments.
#define LOADB(bb, itx)                                                        \
    {                                                                         \
        _Pragma("unroll")                                                     \
        for (int tj = 0; tj < 2; ++tj) {                                      \
            int coll = colchunkbase + (itx) * TILEC + wcol * 32 + tj * 16 + l16; \
            const unsigned char* gB = Fbc + (size_t)coll * 256 + quad * 16;   \
            _Pragma("unroll")                                                 \
            for (int k = 0; k < 4; ++k)                                       \
                bb[tj][k] = *(const bf16x8*)(gB + k * 64);                    \
        }                                                                     \
    }

// Compute one 64-col tile from register set bb: 32 MFMA + diag + epilogue.
#define COMPUTE(bb, itx)                                                      \
    {                                                                         \
        int colbase = colchunkbase + (itx) * TILEC;                           \
        _Pragma("unroll")                                                     \
        for (int tj = 0; tj < 2; ++tj) {                                      \
            floatx4 acc[4];                                                   \
            _Pragma("unroll")                                                 \
            for (int ti = 0; ti < 4; ++ti) acc[ti] = (floatx4){0.f,0.f,0.f,0.f}; \
            _Pragma("unroll")                                                 \
            for (int k = 0; k < 4; ++k)                                       \
                _Pragma("unroll")                                             \
                for (int ti = 0; ti < 4; ++ti)                                \
                    acc[ti] = __builtin_amdgcn_mfma_f32_16x16x32_bf16(        \
                        afrag[ti][k], bb[tj][k], acc[ti], 0, 0, 0);           \
            /* Diagonal capture: wave-uniform, rare (1 per 64 diag cols). */  \
            {                                                                 \
                int ctb = colbase + wcol * 32 + tj * 16;                      \
                unsigned u = (unsigned)(ctb - (rowbase + wrow * 64));         \
                if (u < 64u) {                                                \
                    _Pragma("unroll")                                         \
                    for (int ti2 = 0; ti2 < 4; ++ti2) {                       \
                        if (u == (unsigned)(ti2 * 16)) {                      \
                            _Pragma("unroll")                                 \
                            for (int r = 0; r < 4; ++r)                       \
                                if (l16 == quad * 4 + r)                      \
                                    diag[ctb + l16] = acc[ti2][r];            \
                        }                                                     \
                    }                                                         \
                }                                                             \
            }                                                                 \
            _Pragma("unroll")                                                 \
            for (int ti = 0; ti < 4; ++ti) {                                  \
                _Pragma("unroll")                                             \
                for (int r = 0; r < 4; ++r) {                                 \
                    /* C/D: D[row=quad*4+r][col=l16]; fma+exp2+add */         \
                    float a = acc[ti][r];                                     \
                    e_acc[ti * 4 + r] += fast_exp2(__builtin_fmaf(a, C1F, C2F)); \
                }                                                             \
            }                                                                 \
        }                                                                     \
    }

// ---- 3) fused GEMM + exp partials (reg-prefetched B, barrier-free) ----
__global__ __launch_bounds__(256, 2) void supcon_main(
    const unsigned short* __restrict__ Fb,
    float* __restrict__ e_part, float* __restrict__ diag)
{
    __shared__ float red[128][2];                 // only LDS: cross-wave sum

    const int tid  = threadIdx.x;
    const int lane = tid & 63;
    const int wid  = tid >> 6;
    const int wrow = wid >> 1;
    const int wcol = wid & 1;
    const int quad = lane >> 4;
    const int l16  = lane & 15;

    const int chunk   = blockIdx.x;
    const int rowbase = blockIdx.y * 128;
    const int colchunkbase = chunk * COLCHUNK;

    const unsigned char* Fbc = (const unsigned char*)Fb;

    // A fragments direct from L2 (once per block).
    bf16x8 afrag[4][4];
#pragma unroll
    for (int ti = 0; ti < 4; ++ti) {
        int row = rowbase + wrow * 64 + ti * 16 + l16;
        const unsigned char* gA = Fbc + (size_t)row * 256 + quad * 16;
#pragma unroll
        for (int k = 0; k < 4; ++k)
            afrag[ti][k] = *(const bf16x8*)(gA + k * 64);
    }

    float e_acc[16];
#pragma unroll
    for (int i = 0; i < 16; ++i) e_acc[i] = 0.0f;

    // Double-state B registers, static names only.
    bf16x8 b0[2][4], b1[2][4];
    LOADB(b0, 0);

    for (int it = 0; it < ITERS; it += 2) {
        // Prefetch next tile FIRST (issue-early), compute current (use-late):
        // the compiler keeps the loads in flight across COMPUTE and waits
        // only at the next body's first use.
        LOADB(b1, it + 1);
        COMPUTE(b0, it);
        if (it + 2 < ITERS) LOADB(b0, it + 2);
        COMPUTE(b1, it + 1);
    }

    // reduce across 16 column-lanes (xor over lane bits 0..3)
#pragma unroll
    for (int i = 0; i < 16; ++i) {
        float e = e_acc[i];
#pragma unroll
        for (int m = 1; m < 16; m <<= 1) e += __shfl_xor(e, m, 64);
        if (l16 == 0) {
            int row_local = wrow * 64 + (i >> 2) * 16 + quad * 4 + (i & 3);
            red[row_local][wcol] = e;
        }
    }
    __syncthreads();

    if (tid < 128) {
        size_t idx = (size_t)chunk * BB + (rowbase + tid);
        e_part[idx] = red[tid][0] + red[tid][1];
    }
}

// ---- 4) e partials + p-dot -> scalar loss ----
__global__ __launch_bounds__(256) void supcon_reduce(
    const float* __restrict__ e_part, const unsigned short* __restrict__ Fb,
    const int* __restrict__ labels, const float* __restrict__ g,
    const float* __restrict__ diag,
    float* __restrict__ accbuf, float* __restrict__ out)
{
    // Exact per-class counts over the whole batch (labels in [0,100)).
    __shared__ int cnt[128];
    if (threadIdx.x < 128) cnt[threadIdx.x] = 0;
    __syncthreads();
    for (int i = threadIdx.x; i < BB; i += 256)
        atomicAdd(&cnt[labels[i]], 1);
    __syncthreads();

    int row = blockIdx.x * 256 + threadIdx.x;    // grid 32
    float e = 0.f;
#pragma unroll
    for (int c = 0; c < NC; ++c)
        e += e_part[(size_t)c * BB + row];

    int cls = labels[row];

    // p_i = a_i . g[lab_i]  (bf16-rounded features, fp32 class sums).
    const unsigned short* fr = Fb + (size_t)row * DD;
    const float* gr = g + cls * DD;
    float p0 = 0.f, p1 = 0.f;
#pragma unroll
    for (int q = 0; q < 16; ++q) {
        uint4  u  = ((const uint4*)fr)[q];        // 8 bf16
        float4 ga = ((const float4*)gr)[2 * q];
        float4 gb = ((const float4*)gr)[2 * q + 1];
        p0 = __builtin_fmaf(__uint_as_float(u.x << 16),          ga.x, p0);
        p1 = __builtin_fmaf(__uint_as_float(u.x & 0xFFFF0000u),  ga.y, p1);
        p0 = __builtin_fmaf(__uint_as_float(u.y << 16),          ga.z, p0);
        p1 = __builtin_fmaf(__uint_as_float(u.y & 0xFFFF0000u),  ga.w, p1);
        p0 = __builtin_fmaf(__uint_as_float(u.z << 16),          gb.x, p0);
        p1 = __builtin_fmaf(__uint_as_float(u.z & 0xFFFF0000u),  gb.y, p1);
        p0 = __builtin_fmaf(__uint_as_float(u.w << 16),          gb.z, p0);
        p1 = __builtin_fmaf(__uint_as_float(u.w & 0xFFFF0000u),  gb.w, p1);
    }
    float p = p0 + p1;

    // exact diagonal removal (e: same exp2 instruction on same input as main)
    float d = diag[row];
    e -= fast_exp2(__builtin_fmaf(d, C1F, C2F));
    p -= d;
    int n_i = cnt[cls] - 1;                      // integer-exact positive count

    float contrib = 0.f, vld = 0.f;
    if (n_i > 0) {
        vld = 1.0f;
        contrib = -(p * TEMP_INV / (float)n_i - MSHIFT - logf(e));
    }
#pragma unroll
    for (int m = 1; m < 64; m <<= 1) {
        contrib += __shfl_xor(contrib, m, 64);
        vld     += __shfl_xor(vld, m, 64);
    }
    __shared__ float rl[4], rv[4];
    int lane = threadIdx.x & 63, w = threadIdx.x >> 6;
    if (lane == 0) { rl[w] = contrib; rv[w] = vld; }
    __syncthreads();
    if (threadIdx.x == 0) {
        float L = rl[0] + rl[1] + rl[2] + rl[3];
        float V = rv[0] + rv[1] + rv[2] + rv[3];
        atomicAdd(&accbuf[0], L);
        atomicAdd(&accbuf[1], V);
        __threadfence();
        unsigned t = atomicAdd((unsigned*)accbuf + 2, 1u);
        if (t == 31u) {                      // last block: all adds fenced+done
            float Ls = atomicAdd(&accbuf[0], 0.0f);
            float Vs = atomicAdd(&accbuf[1], 0.0f);
            out[0] = (Vs > 0.5f) ? (Ls / Vs) : 0.0f;
        }
    }
}

extern "C" void kernel_launch(void* const* d_in, const int* in_sizes, int n_in,
                              void* d_out, int out_size, void* d_ws, size_t ws_size,
                              hipStream_t stream)
{
    const void* Fin = d_in[0];
    const void* Lin = d_in[1];

    // ws layout (~6.2 MB; ws is 256 MB per the harness poison-fill size)
    unsigned short* fbf = (unsigned short*)d_ws;                          // 2 MB bf16 copy
    int*   lab      = (int*)((char*)d_ws + (size_t)BB * DD * 2);          // 32 KB
    float* e_part   = (float*)((char*)lab + (size_t)BB * 4);              // NC*B floats (512 KB)
    float* diag     = e_part + (size_t)NC * BB;                           // B floats
    float* g        = diag + BB;                                          // 100*128 floats
    float* accbuf   = g + NCLS * DD;                                      // 3 slots
    int*   cls_cnt  = (int*)(accbuf + 3);                                 // 100 ints
    int*   cls_list = cls_cnt + NCLS;                                     // 100*8192 ints (3.2 MB)

    // Zero class counters + accbuf (412 B; graph-capture legal).
    hipMemsetAsync(accbuf, 0, (3 + NCLS) * 4, stream);

    supcon_convert<<<BB * DD / 4 / 256, 256, 0, stream>>>(
        Fin, Lin, fbf, lab, cls_cnt, cls_list);

    supcon_classsum<<<NCLS, 128, 0, stream>>>(fbf, cls_cnt, cls_list, g);

    dim3 grid(NC, BB / 128);
    supcon_main<<<grid, 256, 0, stream>>>(fbf, e_part, diag);

    supcon_reduce<<<32, 256, 0, stream>>>(e_part, fbf, lab, g, diag, accbuf, (float*)d_out);
}

// Round 12
// 92.431 us; speedup vs baseline: 1.6972x; 1.6972x over previous
//
#include <hip/hip_runtime.h>
#include <hip/hip_bf16.h>

// SupConLoss, B=8192, D=128, T=0.1. Output: single fp32 scalar.
// (r12 = r11 resubmitted unchanged: r11's bench died in the GPU broker —
//  "container failed twice", no counters/absmax — infra failure, not a
//  kernel verdict. Kernel re-audited: fragment addressing, bounds, diag
//  single-writer, disjoint-row writes all check out.)
//
// Pipeline (3 launches):
//   1) supcon_convert — dtype detection (fp32 vs bf16 feats, i64 vs i32
//      labels); writes features ONCE in MFMA-FRAGMENT ORDER: for col-tile
//      T (16 cols) and k-chunk g, a 64-lane x 16B block at
//      frag[((T*4+g)<<10) + lane*16] = B[n=lane&15][k=g*32+(lane>>4)*8+j].
//      Every A/B fragment load in main is then ONE contiguous 1KB
//      global_load_dwordx4 (8 full 128B lines) instead of r9/r10's 16
//      half-used lines per load (Guideline-2 violation = the ~37us stall).
//      Also labels -> int32, accbuf zeroed.
//   2) supcon_main    — fused bf16-MFMA GEMM (F.F^T) + e/p accumulation.
//      Barrier-free, LDS-free, reg-prefetched (1 col-tile ahead). Waves own
//      32 rows each (afrag 32 VGPR) -> room to fold p back in-epilogue
//      (r0 proved VALU headroom), DELETING the class-sum pipeline that cost
//      30-88us in four different forms (r5/r6/r7/r10). Diagonal raw dot
//      captured to ws. e/p partials written per-wave (disjoint rows).
//   3) supcon_reduce  — e/p partials -> loss. n_i from exact label
//      histogram (n_i = cnt[lab_i]-1). Diagonal removed exactly (same exp2
//      instruction on same input). Last-block-atomic finalization (ticket
//      zeroed by convert -> graph-replay safe).
//
// Math: with ANY fixed shift M, per row i:
//   mean_log_prob_i = 10*p_i/n_i - M - log(sum_{j!=i} exp(s_ij - M))
// (shift cancels; M=10.5 >= max s_ij for unit-norm). exp folded to exp2:
// exp(10a-10.5) = exp2(a*C1 + C2).
//
// History:
//  r1: launch_bounds(256,4) -> VGPR=64 spill. Never clamp below live set.
//  r2-r4: LDS-staged variants all ~40-46us (coalesced staging but 2-phase
//      barrier lockstep, m233).
//  r5-r7,r10: four class-sum schemes, all 30-88us latency traps.
//  r8: sched_barrier graft -> regalloc spill (WRITE 74MB).
//  r9/r10: reg-prefetch clean but B-loads gather 16 half-lines/instr ->
//      ~37us stall; NC 8->16 null; OccupancyPercent untrustworthy (fill
//      kernel reads 8.5%). r11: fragment-order pre-swizzle ->
//      coalesced + barrier-free + prefetched simultaneously; p in-main.
//  r11 bench: infra failure (no data). r12: identical resubmit.

#define BB 8192
#define DD 128
#define NCLS 100
#define NC 16                 // column chunks (grid.x): 1024 blocks
#define COLCHUNK (BB / NC)    // 512 cols per WG
#define NT (COLCHUNK / 16)    // 32 col-tiles of 16
#define TEMP_INV 10.0f
#define MSHIFT 10.5f
#define C1F 14.426950408889634f    /* 10*log2(e)    */
#define C2F -15.148297929334116f   /* -10.5*log2(e) */

typedef __bf16 bf16x8 __attribute__((ext_vector_type(8)));
typedef float floatx4 __attribute__((ext_vector_type(4)));

__device__ inline float fast_exp2(float x) {
#if __has_builtin(__builtin_amdgcn_exp2f)
    return __builtin_amdgcn_exp2f(x);
#else
    return exp2f(x);
#endif
}

__device__ inline unsigned short f2bf(float f) {           // RTNE fp32->bf16
    unsigned u = __float_as_uint(f);
    return (unsigned short)((u + 0x7FFFu + ((u >> 16) & 1u)) >> 16);
}

// ---- 1) canonicalize into fragment order (+ detect + labels + zero) ----
// Grid 512 x 256: thread handles one 16B output granule G:
//   T = G>>8 (col-tile), g = (G>>6)&3 (k-chunk), l = G&63 (lane slot)
//   col = T*16 + (l&15); kb = g*32 + (l>>4)*8; 8 bf16 from row `col`.
__global__ __launch_bounds__(256) void supcon_convert(
    const void* __restrict__ fin, const void* __restrict__ lin,
    unsigned short* __restrict__ frag, int* __restrict__ lab,
    float* __restrict__ accbuf)
{
    // Per-wave dtype detection (header reads broadcast from L1).
    int lane = threadIdx.x & 63;
    unsigned ue = ((unsigned)((const unsigned short*)fin)[2 * lane]) << 16;
    float fe = __uint_as_float(ue);
    float ve = fe * fe;
    int odd_or = ((const int*)lin)[2 * lane + 1];
#pragma unroll
    for (int m = 1; m < 64; m <<= 1) {
        ve += __shfl_xor(ve, m, 64);
        odd_or |= __shfl_xor(odd_or, m, 64);
    }
    // true bf16 unit rows: sum sq of 64 even slots of row 0 is ~0.5.
    bool f_bf16 = (ve > 0.05f) && (ve < 4.0f);   // NaN-safe: NaN -> false
    bool l_i64  = (odd_or == 0);

    int G = blockIdx.x * 256 + threadIdx.x;      // 131072 granules x 16B
    int T = G >> 8;
    int g = (G >> 6) & 3;
    int l = G & 63;
    int col = T * 16 + (l & 15);
    int kb  = g * 32 + ((l >> 4) << 3);

    ushort4 o0, o1;
    if (!f_bf16) {
        const float4* src = (const float4*)((const float*)fin + (size_t)col * DD + kb);
        float4 a = src[0], b = src[1];
        o0.x = f2bf(a.x); o0.y = f2bf(a.y); o0.z = f2bf(a.z); o0.w = f2bf(a.w);
        o1.x = f2bf(b.x); o1.y = f2bf(b.y); o1.z = f2bf(b.z); o1.w = f2bf(b.w);
    } else {
        const ushort4* src = (const ushort4*)((const unsigned short*)fin + (size_t)col * DD + kb);
        o0 = src[0]; o1 = src[1];
    }
    ushort4* dst = (ushort4*)(frag + (size_t)G * 8);   // coalesced 16B store
    dst[0] = o0; dst[1] = o1;

    const int* L = (const int*)lin;
    if (blockIdx.x < 32) {
        int li = blockIdx.x * 256 + threadIdx.x;
        lab[li] = l_i64 ? L[2 * li] : L[li];
    }
    if (blockIdx.x == 0 && threadIdx.x == 0) {   // zero last-block finals
        accbuf[0] = 0.0f;                        // loss sum
        accbuf[1] = 0.0f;                        // valid count
        ((unsigned*)accbuf)[2] = 0u;             // ticket
    }
}

// Load B fragments for col-tile `t` (4 k-chunks): ONE coalesced 1KB load
// each, addr = fragbase + ((tile0+t)*4+k)*1024 + lane*16.
#define LOADF(bb, t)                                                          \
    {                                                                         \
        const unsigned char* fb =                                             \
            Fbc + ((size_t)((ctile0 + (t)) * 4) << 10) + lane * 16;           \
        _Pragma("unroll")                                                     \
        for (int k = 0; k < 4; ++k)                                           \
            bb[k] = *(const bf16x8*)(fb + (k << 10));                         \
    }

// Compute one 16-col tile from register set bb: 8 MFMA + diag + epilogue.
#define COMPUTE(bb, t)                                                        \
    {                                                                         \
        int colbase = colchunkbase + (t) * 16;                                \
        floatx4 acc[2];                                                       \
        acc[0] = (floatx4){0.f, 0.f, 0.f, 0.f};                               \
        acc[1] = (floatx4){0.f, 0.f, 0.f, 0.f};                               \
        _Pragma("unroll")                                                     \
        for (int k = 0; k < 4; ++k) {                                         \
            acc[0] = __builtin_amdgcn_mfma_f32_16x16x32_bf16(                 \
                afrag[0][k], bb[k], acc[0], 0, 0, 0);                         \
            acc[1] = __builtin_amdgcn_mfma_f32_16x16x32_bf16(                 \
                afrag[1][k], bb[k], acc[1], 0, 0, 0);                         \
        }                                                                     \
        /* Diagonal capture: wave-uniform, rare (2 tiles per wave total). */  \
        {                                                                     \
            unsigned u = (unsigned)(colbase - (rowbase + wid * 32));          \
            if (u < 32u) {                                                    \
                _Pragma("unroll")                                             \
                for (int ti2 = 0; ti2 < 2; ++ti2) {                           \
                    if (u == (unsigned)(ti2 * 16)) {                          \
                        _Pragma("unroll")                                     \
                        for (int r = 0; r < 4; ++r)                           \
                            if (l16 == quad * 4 + r)                          \
                                diag[colbase + l16] = acc[ti2][r];            \
                    }                                                         \
                }                                                             \
            }                                                                 \
        }                                                                     \
        int lab_c = lab[colbase + l16];                                       \
        _Pragma("unroll")                                                     \
        for (int ti = 0; ti < 2; ++ti) {                                      \
            _Pragma("unroll")                                                 \
            for (int r = 0; r < 4; ++r) {                                     \
                /* C/D: D[row=quad*4+r][col=l16] (m89/m91 verified) */        \
                int i = ti * 4 + r;                                           \
                float a = acc[ti][r];                                         \
                e_acc[i] += fast_exp2(__builtin_fmaf(a, C1F, C2F));           \
                float peq = (lab_c == lab_row[i]) ? 1.0f : 0.0f;              \
                p_acc[i] = __builtin_fmaf(peq, a, p_acc[i]);                  \
            }                                                                 \
        }                                                                     \
    }

// ---- 2) fused GEMM + e/p partials (coalesced reg-prefetch, no LDS) ----
__global__ __launch_bounds__(256, 2) void supcon_main(
    const unsigned short* __restrict__ Fb, const int* __restrict__ lab,
    float* __restrict__ e_part, float* __restrict__ p_part,
    float* __restrict__ diag)
{
    const int tid  = threadIdx.x;
    const int lane = tid & 63;
    const int wid  = tid >> 6;                   // wave owns 32 rows
    const int quad = lane >> 4;
    const int l16  = lane & 15;

    const int chunk   = blockIdx.x;
    const int rowbase = blockIdx.y * 128;
    const int colchunkbase = chunk * COLCHUNK;
    const int ctile0  = colchunkbase >> 4;

    const unsigned char* Fbc = (const unsigned char*)Fb;

    // A fragments (2 row-tiles x 4 k-chunks) — coalesced 1KB loads.
    bf16x8 afrag[2][4];
#pragma unroll
    for (int ti = 0; ti < 2; ++ti) {
        int rt = (rowbase >> 4) + wid * 2 + ti;
        const unsigned char* fa = Fbc + ((size_t)(rt * 4) << 10) + lane * 16;
#pragma unroll
        for (int k = 0; k < 4; ++k)
            afrag[ti][k] = *(const bf16x8*)(fa + (k << 10));
    }

    int lab_row[8];
#pragma unroll
    for (int ti = 0; ti < 2; ++ti)
#pragma unroll
        for (int r = 0; r < 4; ++r)
            lab_row[ti * 4 + r] = lab[rowbase + wid * 32 + ti * 16 + quad * 4 + r];

    float e_acc[8], p_acc[8];
#pragma unroll
    for (int i = 0; i < 8; ++i) { e_acc[i] = 0.0f; p_acc[i] = 0.0f; }

    // Double-state B registers, static names only (rule #20).
    bf16x8 b0[4], b1[4];
    LOADF(b0, 0);

    for (int t = 0; t < NT; t += 2) {
        LOADF(b1, t + 1);                // issue-early
        COMPUTE(b0, t);                  // use-late
        if (t + 2 < NT) LOADF(b0, t + 2);
        COMPUTE(b1, t + 1);
    }

    // Waves own disjoint rows -> no cross-wave reduce, no LDS, no barrier.
    // Reduce over the 16 column-lanes (xor in l16 bits), then l16==0 lanes
    // (one per quad) write 8 rows each.
#pragma unroll
    for (int i = 0; i < 8; ++i) {
        float e = e_acc[i], p = p_acc[i];
#pragma unroll
        for (int m = 1; m < 16; m <<= 1) {
            e += __shfl_xor(e, m, 64);
            p += __shfl_xor(p, m, 64);
        }
        if (l16 == 0) {
            int row = rowbase + wid * 32 + (i >> 2) * 16 + quad * 4 + (i & 3);
            e_part[(size_t)chunk * BB + row] = e;
            p_part[(size_t)chunk * BB + row] = p;
        }
    }
}

// ---- 3) e/p partials -> scalar loss ----
__global__ __launch_bounds__(256) void supcon_reduce(
    const float* __restrict__ e_part, const float* __restrict__ p_part,
    const int* __restrict__ labels, const float* __restrict__ diag,
    float* __restrict__ accbuf, float* __restrict__ out)
{
    // Exact per-class counts over the whole batch (labels in [0,100)).
    __shared__ int cnt[128];
    if (threadIdx.x < 128) cnt[threadIdx.x] = 0;
    __syncthreads();
    for (int i = threadIdx.x; i < BB; i += 256)
        atomicAdd(&cnt[labels[i]], 1);
    __syncthreads();

    int row = blockIdx.x * 256 + threadIdx.x;    // grid 32
    float e = 0.f, p = 0.f;
#pragma unroll
    for (int c = 0; c < NC; ++c) {
        size_t idx = (size_t)c * BB + row;
        e += e_part[idx]; p += p_part[idx];
    }
    // exact diagonal removal (e: same exp2 instruction on same input as main)
    float d = diag[row];
    e -= fast_exp2(__builtin_fmaf(d, C1F, C2F));
    p -= d;
    int n_i = cnt[labels[row]] - 1;              // integer-exact positive count

    float contrib = 0.f, vld = 0.f;
    if (n_i > 0) {
        vld = 1.0f;
        contrib = -(p * TEMP_INV / (float)n_i - MSHIFT - logf(e));
    }
#pragma unroll
    for (int m = 1; m < 64; m <<= 1) {
        contrib += __shfl_xor(contrib, m, 64);
        vld     += __shfl_xor(vld, m, 64);
    }
    __shared__ float rl[4], rv[4];
    int lane = threadIdx.x & 63, w = threadIdx.x >> 6;
    if (lane == 0) { rl[w] = contrib; rv[w] = vld; }
    __syncthreads();
    if (threadIdx.x == 0) {
        float L = rl[0] + rl[1] + rl[2] + rl[3];
        float V = rv[0] + rv[1] + rv[2] + rv[3];
        atomicAdd(&accbuf[0], L);
        atomicAdd(&accbuf[1], V);
        __threadfence();
        unsigned t = atomicAdd((unsigned*)accbuf + 2, 1u);
        if (t == 31u) {                      // last block: all adds fenced+done
            float Ls = atomicAdd(&accbuf[0], 0.0f);
            float Vs = atomicAdd(&accbuf[1], 0.0f);
            out[0] = (Vs > 0.5f) ? (Ls / Vs) : 0.0f;
        }
    }
}

extern "C" void kernel_launch(void* const* d_in, const int* in_sizes, int n_in,
                              void* d_out, int out_size, void* d_ws, size_t ws_size,
                              hipStream_t stream)
{
    const void* Fin = d_in[0];
    const void* Lin = d_in[1];

    // ws layout (~3.1 MB)
    unsigned short* frag = (unsigned short*)d_ws;                         // 2 MB fragment-order bf16
    int*   lab      = (int*)((char*)d_ws + (size_t)BB * DD * 2);          // 32 KB
    float* e_part   = (float*)((char*)lab + (size_t)BB * 4);              // NC*B floats (512 KB)
    float* p_part   = e_part + (size_t)NC * BB;                           // 512 KB
    float* diag     = p_part + (size_t)NC * BB;                           // B floats
    float* accbuf   = diag + BB;                                          // 3 slots

    supcon_convert<<<BB * DD / 8 / 256, 256, 0, stream>>>(Fin, Lin, frag, lab, accbuf);

    dim3 grid(NC, BB / 128);
    supcon_main<<<grid, 256, 0, stream>>>(frag, lab, e_part, p_part, diag);

    supcon_reduce<<<32, 256, 0, stream>>>(e_part, p_part, lab, diag, accbuf, (float*)d_out);
}